// Round 3
// baseline (595.784 us; speedup 1.0000x reference)
//
#include <hip/hip_runtime.h>
#include <hip/hip_bf16.h>
#include <cstdint>

#define T_TOK 8192
#define DDIM 1024
#define FDIM 4096
#define NEXP 8
#define MAX_TILES 40  // sum ceil(counts[e]/256) <= 8192/256 + 7 = 39

typedef short short8 __attribute__((ext_vector_type(8)));
typedef float floatx4 __attribute__((ext_vector_type(4)));

// round-to-nearest-even f32 -> bf16
__device__ __forceinline__ short f2bf(float f) {
  unsigned u = __float_as_uint(f);
  unsigned r = (u + 0x7fffu + ((u >> 16) & 1u)) >> 16;
  return (short)r;
}

// async global -> LDS, 16B per lane (dest = wave-uniform base + lane*16)
__device__ __forceinline__ void load_lds16(const void* g, void* l) {
  __builtin_amdgcn_global_load_lds(
      (__attribute__((address_space(1))) unsigned int*)g,
      (__attribute__((address_space(3))) unsigned int*)l, 16, 0, 0);
}

// ---------------- fused prep: router + both weight transposes -------------
// grid layout (1D): [0,2048) router blocks (4 tokens each);
// [2048,10240) w1 transpose tiles; [10240,18432) w2 transpose tiles.
// All independent; fusing saves 2 dispatch gaps and co-schedules the
// memory-bound transposes with the router's compute.
__global__ __launch_bounds__(256) void prep_kernel(
    const float* __restrict__ x, const float* __restrict__ rw,
    const float* __restrict__ rb, const float* __restrict__ w1,
    const float* __restrict__ w2, short* __restrict__ W1T,
    short* __restrict__ W2T, int* __restrict__ expert_t,
    float* __restrict__ gate_t, short* __restrict__ Xbf) {
  __shared__ __align__(16) char smem[32768];
  int bid = blockIdx.x;
  int tid = threadIdx.x;
  if (bid < 2048) {
    // ---- router: one wave per token, no atomics; fuses x -> bf16 (Xbf)
    float* w = (float*)smem;
    for (int i = tid; i < NEXP * DDIM; i += 256) w[i] = rw[i];
    __syncthreads();
    int wid = tid >> 6, lane = tid & 63;
    int t = bid * 4 + wid;
    const float4* xr = (const float4*)(x + (size_t)t * DDIM);
    uint2* xd = (uint2*)(Xbf + (size_t)t * DDIM);
    float acc[NEXP];
#pragma unroll
    for (int e = 0; e < NEXP; e++) acc[e] = 0.f;
#pragma unroll
    for (int i = 0; i < 4; i++) {
      float4 v = xr[lane + 64 * i];
      uint2 p;
      p.x = (unsigned)(unsigned short)f2bf(v.x) |
            ((unsigned)(unsigned short)f2bf(v.y) << 16);
      p.y = (unsigned)(unsigned short)f2bf(v.z) |
            ((unsigned)(unsigned short)f2bf(v.w) << 16);
      xd[lane + 64 * i] = p;
      int col = (lane + 64 * i) * 4;
#pragma unroll
      for (int e = 0; e < NEXP; e++) {
        const float4 wv = *(const float4*)&w[e * DDIM + col];
        acc[e] += v.x * wv.x + v.y * wv.y + v.z * wv.z + v.w * wv.w;
      }
    }
#pragma unroll
    for (int e = 0; e < NEXP; e++) {
#pragma unroll
      for (int off = 32; off > 0; off >>= 1) acc[e] += __shfl_xor(acc[e], off);
    }
    if (lane == 0) {
      float l[NEXP];
#pragma unroll
      for (int e = 0; e < NEXP; e++) l[e] = acc[e] + rb[e];
      int best = 0;
      float lm = l[0];
#pragma unroll
      for (int e = 1; e < NEXP; e++)
        if (l[e] > lm) { lm = l[e]; best = e; }
      float s = 0.f;
#pragma unroll
      for (int e = 0; e < NEXP; e++) s += expf(l[e] - lm);
      expert_t[t] = best;
      gate_t[t] = 1.f / s;  // softmax prob of argmax
    }
  } else {
    // ---- transpose+convert: [E][R][C] f32 -> [E][C][R] bf16
    const float* src;
    short* dst;
    int R, C, bx, by, e;
    int idx = bid - 2048;
    if (idx < 8192) {
      e = idx >> 10;
      int rem = idx & 1023;
      bx = rem & 63;
      by = rem >> 6;
      src = w1; dst = W1T; R = DDIM; C = FDIM;
    } else {
      idx -= 8192;
      e = idx >> 10;
      int rem = idx & 1023;
      bx = rem & 15;
      by = rem >> 4;
      src = w2; dst = W2T; R = FDIM; C = DDIM;
    }
    float (*tile)[65] = (float(*)[65])smem;
    long long base = (long long)e * R * C;
    const float* s = src + base;
    short* d = dst + base;
    int r0 = by * 64, c0 = bx * 64;
#pragma unroll
    for (int it = 0; it < 4; it++) {
      int i = tid + it * 256;
      int r = i >> 4, c4 = (i & 15) << 2;
      float4 v = *(const float4*)(s + (size_t)(r0 + r) * C + c0 + c4);
      tile[r][c4] = v.x;
      tile[r][c4 + 1] = v.y;
      tile[r][c4 + 2] = v.z;
      tile[r][c4 + 3] = v.w;
    }
    __syncthreads();
#pragma unroll
    for (int it = 0; it < 2; it++) {
      int i = tid + it * 256;
      int cc = i >> 3, rr = (i & 7) << 3;
      short8 o;
#pragma unroll
      for (int w = 0; w < 8; w++) o[w] = f2bf(tile[rr + w][cc]);
      *(short8*)(d + (size_t)(c0 + cc) * R + r0 + rr) = o;
    }
  }
}

// ------- finalize: one block, 1024 threads (16 waves), 8 chunks of 1024 tok.
// Ballot histograms + wave scan -> per-token positions (no global atomics),
// counts/offsets, probsum via shfl reduce, aux loss, tile list, and the
// tok_of_row / gate_row scatter.
__global__ __launch_bounds__(1024) void finalize_kernel(
    const int* __restrict__ expert_t, const float* __restrict__ gate_t,
    int* __restrict__ counts, int* __restrict__ offsets,
    float* __restrict__ loss_out, int* __restrict__ tileE,
    int* __restrict__ tileM, int* __restrict__ ntiles,
    int* __restrict__ tok_of_row, float* __restrict__ gate_row) {
  __shared__ int wc[16][NEXP];     // per-wave per-expert count (this chunk)
  __shared__ int wbase[16][NEXP];  // exclusive scan result per wave
  __shared__ int baseL[NEXP];      // running total across chunks
  __shared__ float psumL[NEXP];
  __shared__ int offsL[NEXP];
  int tid = threadIdx.x;
  int wid = tid >> 6, lane = tid & 63;
  if (tid < NEXP) {
    baseL[tid] = 0;
    psumL[tid] = 0.f;
  }
  __syncthreads();

  int exl[8], posl[8];
  float gl[8];
  float wpsum[NEXP];
#pragma unroll
  for (int e = 0; e < NEXP; e++) wpsum[e] = 0.f;
  unsigned long long lt = (1ull << lane) - 1ull;

#pragma unroll
  for (int c = 0; c < 8; c++) {
    int t = c * 1024 + tid;
    int ex = expert_t[t];
    float g = gate_t[t];
    exl[c] = ex;
    gl[c] = g;
    int myPrefix = 0;
#pragma unroll
    for (int e = 0; e < NEXP; e++) {
      unsigned long long b = __ballot(ex == e);
      if (lane == e) wc[wid][e] = __popcll(b);
      if (ex == e) myPrefix = __popcll(b & lt);
      float v = (ex == e) ? g : 0.f;
#pragma unroll
      for (int off = 32; off > 0; off >>= 1) v += __shfl_xor(v, off);
      if (lane == 0) wpsum[e] += v;
    }
    __syncthreads();
    if (tid < NEXP) {
      int run = baseL[tid];
      for (int w = 0; w < 16; w++) {
        wbase[w][tid] = run;
        run += wc[w][tid];
      }
      baseL[tid] = run;
    }
    __syncthreads();
    posl[c] = wbase[wid][ex] + myPrefix;
  }

  if (lane == 0) {
#pragma unroll
    for (int e = 0; e < NEXP; e++) atomicAdd(&psumL[e], wpsum[e]);
  }
  __syncthreads();

  if (tid == 0) {
    int off = 0, nt = 0;
    float loss = 0.f;
    for (int e = 0; e < NEXP; e++) {
      int cnt = baseL[e];
      counts[e] = cnt;
      offsets[e] = off;
      offsL[e] = off;
      off += cnt;
      loss += ((float)cnt / (float)T_TOK) *
              (psumL[e] / ((float)T_TOK * (float)T_TOK));
      for (int m = 0; m < cnt; m += 256) {
        tileE[nt] = e;
        tileM[nt] = m;
        nt++;
      }
    }
    offsets[NEXP] = off;
    *ntiles = nt;
    *loss_out = loss * 3e-6f * (float)NEXP;
  }
  __syncthreads();

#pragma unroll
  for (int c = 0; c < 8; c++) {
    int t = c * 1024 + tid;
    int row = offsL[exl[c]] + posl[c];
    tok_of_row[row] = t;
    gate_row[row] = gl[c];
  }
}

// ---------------- 256x256 bf16 GEMM, 1-barrier-per-K-tile schedule --------
// 8 waves (2M x 4N), BK=64, double-buffered 128 KiB LDS, XOR-swizzled chunks:
// LDS slot (row r, 16B-chunk c) holds global k-chunk (c ^ (r&7)); write side
// stays linear (global_load_lds), swizzle applied to the global source addr.
// Per K-tile: ONE __syncthreads (its vmcnt(0) drains loads issued a full
// tile earlier -> cheap), then stage all 8 half-tiles of tile t+1, then 4
// quadrant groups of {12 ds_read_b128 + 16 MFMA} that the compiler pipelines
// with fine-grained lgkmcnt. 64 MFMA per barrier vs 16 before.
template <int MH, int NH>
__device__ __forceinline__ void quad_mfma(const char* Ab, const char* Bb,
                                          floatx4 (&acc)[8][4], int wm,
                                          int wn, int lane) {
  int l15 = lane & 15, quad = lane >> 4, low3 = lane & 7;
  short8 af[4][2], bv[2][2];
#pragma unroll
  for (int i = 0; i < 4; i++) {
    int row = MH * 128 + wm * 64 + i * 16 + l15;
#pragma unroll
    for (int ks = 0; ks < 2; ks++)
      af[i][ks] =
          *(const short8*)(Ab + row * 128 + (((ks * 4 + quad) ^ low3) << 4));
  }
#pragma unroll
  for (int j = 0; j < 2; j++) {
    int col = NH * 128 + wn * 32 + j * 16 + l15;
#pragma unroll
    for (int ks = 0; ks < 2; ks++)
      bv[j][ks] =
          *(const short8*)(Bb + col * 128 + (((ks * 4 + quad) ^ low3) << 4));
  }
  __builtin_amdgcn_s_setprio(1);
#pragma unroll
  for (int ks = 0; ks < 2; ks++)
#pragma unroll
    for (int i = 0; i < 4; i++)
#pragma unroll
      for (int j = 0; j < 2; j++)
        acc[MH * 4 + i][NH * 2 + j] = __builtin_amdgcn_mfma_f32_16x16x32_bf16(
            af[i][ks], bv[j][ks], acc[MH * 4 + i][NH * 2 + j], 0, 0, 0);
  __builtin_amdgcn_s_setprio(0);
}

template <int KDIM, int NDIM, bool FFN1>
__global__ __launch_bounds__(512, 1) void gemm_kernel(
    const short* __restrict__ A, const short* __restrict__ Bw,
    short* __restrict__ Hout, float* __restrict__ Out,
    const int* __restrict__ counts, const int* __restrict__ offsets,
    const int* __restrict__ tok_of_row, const float* __restrict__ gate_row,
    const int* __restrict__ tileE, const int* __restrict__ tileM,
    const int* __restrict__ ntiles) {
  constexpr int GX = NDIM / 256;
  constexpr int NWG = GX * MAX_TILES;
  static_assert(NWG % 8 == 0, "bijective XCD swizzle needs nwg%8==0");
  constexpr int Q = NWG / 8;
  int flat = blockIdx.y * GX + blockIdx.x;
  int wg = (flat & 7) * Q + (flat >> 3);  // XCD-chunked, bijective
  int ti = wg / GX;
  int nb = wg - ti * GX;
  if (ti >= *ntiles) return;
  int e = tileE[ti], m0 = tileM[ti];
  int Me = counts[e], rowBase = offsets[e];
  int n0 = nb * 256;

  // LDS: [A buf0 32K][A buf1 32K][B buf0 32K][B buf1 32K] = 128 KiB
  __shared__ short lds[65536];

  int tid = threadIdx.x;
  int wid = tid >> 6, lane = tid & 63;
  int wm = wid >> 2, wn = wid & 3;

  // staging geometry: thread covers one 16B chunk per half-stage;
  // row rt = tid>>3, slot chunk tid&7, swizzled source chunk cs.
  int rt = tid >> 3;
  int cs = (tid & 7) ^ (rt & 7);

  auto aPtr = [&](int mh, int s) {
    int r = m0 + mh * 128 + s * 64 + rt;
    if (r > Me - 1) r = Me - 1;  // clamp pad rows to a valid row
    size_t arow;
    if constexpr (FFN1)
      arow = (size_t)tok_of_row[rowBase + r];  // token-ordered Xbf
    else
      arow = (size_t)(rowBase + r);  // expert-sorted Hbuf
    return A + arow * KDIM + cs * 8;
  };
  auto bPtr = [&](int mh, int s) {
    int r = n0 + mh * 128 + s * 64 + rt;
    return Bw + ((size_t)e * NDIM + r) * (size_t)KDIM + cs * 8;
  };
  const short* pA0a = aPtr(0, 0);
  const short* pA0b = aPtr(0, 1);
  const short* pA1a = aPtr(1, 0);
  const short* pA1b = aPtr(1, 1);
  const short* pB0a = bPtr(0, 0);
  const short* pB0b = bPtr(0, 1);
  const short* pB1a = bPtr(1, 0);
  const short* pB1b = bPtr(1, 1);

  floatx4 acc[8][4];
#pragma unroll
  for (int i = 0; i < 8; i++)
#pragma unroll
    for (int j = 0; j < 4; j++) acc[i][j] = floatx4{0.f, 0.f, 0.f, 0.f};

#define STAGE2(P0, P1, OFF)                               \
  load_lds16(P0, (char*)lds + (OFF) + wid * 1024);        \
  load_lds16(P1, (char*)lds + (OFF) + 8192 + wid * 1024); \
  P0 += 64;                                               \
  P1 += 64;

  // prologue: tile 0 into buf 0
  STAGE2(pA0a, pA0b, 0)
  STAGE2(pB0a, pB0b, 65536)
  STAGE2(pA1a, pA1b, 16384)
  STAGE2(pB1a, pB1b, 65536 + 16384)

  constexpr int NT = KDIM / 64;
  int cur = 0;
  for (int t = 0; t < NT; ++t) {
    int nxt = cur ^ 1;
    const char* Ab = (const char*)lds + cur * 32768;
    const char* Bb = (const char*)lds + 65536 + cur * 32768;
    // drains vmcnt(0)+lgkmcnt(0) then s_barrier; the vmem queue holds only
    // tile t's loads (issued one full tile-body ago) -> near-free drain.
    __syncthreads();
    if (t + 1 < NT) {
      STAGE2(pA0a, pA0b, nxt * 32768)
      STAGE2(pB0a, pB0b, 65536 + nxt * 32768)
      STAGE2(pA1a, pA1b, 16384 + nxt * 32768)
      STAGE2(pB1a, pB1b, 65536 + 16384 + nxt * 32768)
    }
    quad_mfma<0, 0>(Ab, Bb, acc, wm, wn, lane);
    quad_mfma<1, 0>(Ab, Bb, acc, wm, wn, lane);
    quad_mfma<0, 1>(Ab, Bb, acc, wm, wn, lane);
    quad_mfma<1, 1>(Ab, Bb, acc, wm, wn, lane);
    cur = nxt;
  }
#undef STAGE2

  // epilogue. C/D layout: col = lane&15, row = (lane>>4)*4 + reg  [m89]
  int l15 = lane & 15;
#pragma unroll
  for (int i = 0; i < 8; i++) {
    int mb = (i >> 2) * 128 + wm * 64 + (i & 3) * 16 + ((lane >> 4) << 2);
#pragma unroll
    for (int r = 0; r < 4; r++) {
      int m = m0 + mb + r;
      if (m < Me) {
        int grow = rowBase + m;
        if constexpr (FFN1) {
#pragma unroll
          for (int j = 0; j < 4; j++) {
            float v = acc[i][j][r];
            v = v > 0.f ? v : 0.f;
            Hout[(size_t)grow * NDIM + n0 + (j >> 1) * 128 + wn * 32 +
                 (j & 1) * 16 + l15] = f2bf(v);
          }
        } else {
          int tk = tok_of_row[grow];
          float g = gate_row[grow];
#pragma unroll
          for (int j = 0; j < 4; j++)
            Out[(size_t)tk * NDIM + n0 + (j >> 1) * 128 + wn * 32 +
                (j & 1) * 16 + l15] = acc[i][j][r] * g;
        }
      }
    }
  }
}

extern "C" void kernel_launch(void* const* d_in, const int* in_sizes, int n_in,
                              void* d_out, int out_size, void* d_ws,
                              size_t ws_size, hipStream_t stream) {
  const float* x = (const float*)d_in[0];
  const float* w1 = (const float*)d_in[1];
  const float* w2 = (const float*)d_in[2];
  const float* rw = (const float*)d_in[3];
  const float* rb = (const float*)d_in[4];
  float* out = (float*)d_out;
  float* loss_out = out + (out_size - 1);  // loss scalar at tail

  char* ws = (char*)d_ws;
  size_t o = 0;
  auto alloc = [&](size_t bytes) {
    char* p = ws + o;
    o += (bytes + 255) & ~(size_t)255;
    return p;
  };
  short* W1T = (short*)alloc((size_t)NEXP * FDIM * DDIM * 2);  // [E][F][D] bf16
  short* W2T = (short*)alloc((size_t)NEXP * DDIM * FDIM * 2);  // [E][D][F] bf16
  short* Xbf = (short*)alloc((size_t)T_TOK * DDIM * 2);        // token-order x
  short* Hbuf = (short*)alloc((size_t)T_TOK * FDIM * 2);       // relu(h) bf16
  int* tok_of_row = (int*)alloc(T_TOK * 4);
  float* gate_row = (float*)alloc(T_TOK * 4);
  int* expert_t = (int*)alloc(T_TOK * 4);
  float* gate_t = (float*)alloc(T_TOK * 4);
  int* counts = (int*)alloc(64);
  int* offsets = (int*)alloc(64);
  int* tileE = (int*)alloc(MAX_TILES * 4);
  int* tileM = (int*)alloc(MAX_TILES * 4);
  int* ntiles = (int*)alloc(64);

  // fused router + w1/w2 transpose-convert (one dispatch)
  prep_kernel<<<2048 + 8192 + 8192, 256, 0, stream>>>(
      x, rw, rb, w1, w2, W1T, W2T, expert_t, gate_t, Xbf);

  finalize_kernel<<<1, 1024, 0, stream>>>(expert_t, gate_t, counts, offsets,
                                          loss_out, tileE, tileM, ntiles,
                                          tok_of_row, gate_row);

  // FFN1: [n_e,1024] @ [1024,4096] -> relu -> Hbuf bf16 (A via tok_of_row)
  gemm_kernel<DDIM, FDIM, true>
      <<<dim3(FDIM / 256, MAX_TILES), 512, 0, stream>>>(
          Xbf, W1T, Hbuf, nullptr, counts, offsets, tok_of_row, nullptr,
          tileE, tileM, ntiles);
  // FFN2: [n_e,4096] @ [4096,1024] -> *gate -> scatter to out fp32
  gemm_kernel<FDIM, DDIM, false>
      <<<dim3(DDIM / 256, MAX_TILES), 512, 0, stream>>>(
          Hbuf, W2T, nullptr, out, counts, offsets, tok_of_row, gate_row,
          tileE, tileM, ntiles);
}

// Round 4
// 542.582 us; speedup vs baseline: 1.0981x; 1.0981x over previous
//
#include <hip/hip_runtime.h>
#include <hip/hip_bf16.h>
#include <cstdint>

#define T_TOK 8192
#define DDIM 1024
#define FDIM 4096
#define NEXP 8
#define MAX_TILES 40  // sum ceil(counts[e]/256) <= 8192/256 + 7 = 39

typedef short short8 __attribute__((ext_vector_type(8)));
typedef float floatx4 __attribute__((ext_vector_type(4)));

// round-to-nearest-even f32 -> bf16
__device__ __forceinline__ short f2bf(float f) {
  unsigned u = __float_as_uint(f);
  unsigned r = (u + 0x7fffu + ((u >> 16) & 1u)) >> 16;
  return (short)r;
}

// async global -> LDS, 16B per lane (dest = wave-uniform base + lane*16)
__device__ __forceinline__ void load_lds16(const void* g, void* l) {
  __builtin_amdgcn_global_load_lds(
      (__attribute__((address_space(1))) unsigned int*)g,
      (__attribute__((address_space(3))) unsigned int*)l, 16, 0, 0);
}

// ---------------- router: one wave per token, NO atomics ----------------
// Fuses x -> bf16 conversion (token-ordered Xbf); expert-sort is virtual via
// tok_of_row indirection in FFN1 staging.
__global__ __launch_bounds__(256) void router_kernel(
    const float* __restrict__ x, const float* __restrict__ rw,
    const float* __restrict__ rb, int* __restrict__ expert_t,
    float* __restrict__ gate_t, short* __restrict__ Xbf) {
  __shared__ float w[NEXP * DDIM];  // 32 KiB
  int tid = threadIdx.x;
  for (int i = tid; i < NEXP * DDIM; i += 256) w[i] = rw[i];
  __syncthreads();
  int wid = tid >> 6, lane = tid & 63;
  int t = blockIdx.x * 4 + wid;
  const float4* xr = (const float4*)(x + (size_t)t * DDIM);
  uint2* xd = (uint2*)(Xbf + (size_t)t * DDIM);
  float acc[NEXP];
#pragma unroll
  for (int e = 0; e < NEXP; e++) acc[e] = 0.f;
#pragma unroll
  for (int i = 0; i < 4; i++) {
    float4 v = xr[lane + 64 * i];
    uint2 p;
    p.x = (unsigned)(unsigned short)f2bf(v.x) |
          ((unsigned)(unsigned short)f2bf(v.y) << 16);
    p.y = (unsigned)(unsigned short)f2bf(v.z) |
          ((unsigned)(unsigned short)f2bf(v.w) << 16);
    xd[lane + 64 * i] = p;
    int col = (lane + 64 * i) * 4;
#pragma unroll
    for (int e = 0; e < NEXP; e++) {
      const float4 wv = *(const float4*)&w[e * DDIM + col];
      acc[e] += v.x * wv.x + v.y * wv.y + v.z * wv.z + v.w * wv.w;
    }
  }
#pragma unroll
  for (int e = 0; e < NEXP; e++) {
#pragma unroll
    for (int off = 32; off > 0; off >>= 1) acc[e] += __shfl_xor(acc[e], off);
  }
  if (lane == 0) {
    float l[NEXP];
#pragma unroll
    for (int e = 0; e < NEXP; e++) l[e] = acc[e] + rb[e];
    int best = 0;
    float lm = l[0];
#pragma unroll
    for (int e = 1; e < NEXP; e++)
      if (l[e] > lm) { lm = l[e]; best = e; }
    float s = 0.f;
#pragma unroll
    for (int e = 0; e < NEXP; e++) s += expf(l[e] - lm);
    expert_t[t] = best;
    gate_t[t] = 1.f / s;  // softmax prob of argmax
  }
}

// ------- transfin: block 0 = finalize (2-pass ballot scan, 4 waves);
// blocks 1..16384 = weight transpose+convert tiles. The transpose blocks are
// independent of the finalize, so the serial scan hides under ~100us of
// transpose work instead of being a standalone near-idle dispatch.
__global__ __launch_bounds__(256) void transfin_kernel(
    const float* __restrict__ w1, const float* __restrict__ w2,
    short* __restrict__ W1T, short* __restrict__ W2T,
    const int* __restrict__ expert_t, const float* __restrict__ gate_t,
    int* __restrict__ counts, int* __restrict__ offsets,
    float* __restrict__ loss_out, int* __restrict__ tileE,
    int* __restrict__ tileM, int* __restrict__ ntiles,
    int* __restrict__ tok_of_row, float* __restrict__ gate_row) {
  __shared__ __align__(16) char smem[64 * 65 * 4];
  int tid = threadIdx.x;
  if (blockIdx.x == 0) {
    // ---- finalize: wave w owns tokens [2048w, 2048w+2048)
    int* wcnt_s = (int*)smem;              // [4][NEXP]
    float* wps_s = (float*)(smem + 128);   // [4][NEXP]
    int* wbase_s = (int*)(smem + 256);     // [4][NEXP]
    int* offs_s = (int*)(smem + 384);      // [NEXP]
    int wid = tid >> 6, lane = tid & 63;
    unsigned long long lt = (1ull << lane) - 1ull;
    int cnt[NEXP];
    float ps[NEXP];
#pragma unroll
    for (int e = 0; e < NEXP; e++) {
      cnt[e] = 0;
      ps[e] = 0.f;
    }
    int tbase = wid * 2048;
    for (int c = 0; c < 32; c++) {
      int t = tbase + c * 64 + lane;
      int ex = expert_t[t];
      float g = gate_t[t];
#pragma unroll
      for (int e = 0; e < NEXP; e++) {
        unsigned long long b = __ballot(ex == e);
        cnt[e] += __popcll(b);
        float v = (ex == e) ? g : 0.f;
#pragma unroll
        for (int off = 32; off > 0; off >>= 1) v += __shfl_xor(v, off);
        ps[e] += v;  // butterfly: all lanes hold the sum
      }
    }
    if (lane == 0) {
#pragma unroll
      for (int e = 0; e < NEXP; e++) {
        wcnt_s[wid * NEXP + e] = cnt[e];
        wps_s[wid * NEXP + e] = ps[e];
      }
    }
    __syncthreads();
    if (tid < NEXP) {
      int run = 0;
      for (int w = 0; w < 4; w++) {
        wbase_s[w * NEXP + tid] = run;
        run += wcnt_s[w * NEXP + tid];
      }
      counts[tid] = run;
    }
    __syncthreads();
    if (tid == 0) {
      int off = 0, nt = 0;
      float loss = 0.f;
      for (int e = 0; e < NEXP; e++) {
        int cn = counts[e];
        offsets[e] = off;
        offs_s[e] = off;
        float psum = wps_s[0 * NEXP + e] + wps_s[1 * NEXP + e] +
                     wps_s[2 * NEXP + e] + wps_s[3 * NEXP + e];
        loss += ((float)cn / (float)T_TOK) *
                (psum / ((float)T_TOK * (float)T_TOK));
        off += cn;
        for (int m = 0; m < cn; m += 256) {
          tileE[nt] = e;
          tileM[nt] = m;
          nt++;
        }
      }
      offsets[NEXP] = off;
      *ntiles = nt;
      *loss_out = loss * 3e-6f * (float)NEXP;
    }
    __syncthreads();
    // pass 2: positions + scatter (per-wave independent, no barriers)
    int runl[NEXP];
#pragma unroll
    for (int e = 0; e < NEXP; e++) runl[e] = 0;
    for (int c = 0; c < 32; c++) {
      int t = tbase + c * 64 + lane;
      int ex = expert_t[t];
      int pre = 0;
#pragma unroll
      for (int e = 0; e < NEXP; e++) {
        unsigned long long b = __ballot(ex == e);
        if (ex == e) pre = __popcll(b & lt) + runl[e];
        runl[e] += __popcll(b);
      }
      int row = offs_s[ex] + wbase_s[wid * NEXP + ex] + pre;
      tok_of_row[row] = t;
      gate_row[row] = gate_t[t];
    }
  } else {
    // ---- transpose+convert: [E][R][C] f32 -> [E][C][R] bf16
    const float* src;
    short* dst;
    int R, C, bx, by, e;
    int idx = blockIdx.x - 1;
    if (idx < 8192) {
      e = idx >> 10;
      int rem = idx & 1023;
      bx = rem & 63;
      by = rem >> 6;
      src = w1; dst = W1T; R = DDIM; C = FDIM;
    } else {
      idx -= 8192;
      e = idx >> 10;
      int rem = idx & 1023;
      bx = rem & 15;
      by = rem >> 4;
      src = w2; dst = W2T; R = FDIM; C = DDIM;
    }
    float (*tile)[65] = (float(*)[65])smem;
    long long base = (long long)e * R * C;
    const float* s = src + base;
    short* d = dst + base;
    int r0 = by * 64, c0 = bx * 64;
#pragma unroll
    for (int it = 0; it < 4; it++) {
      int i = tid + it * 256;
      int r = i >> 4, c4 = (i & 15) << 2;
      float4 v = *(const float4*)(s + (size_t)(r0 + r) * C + c0 + c4);
      tile[r][c4] = v.x;
      tile[r][c4 + 1] = v.y;
      tile[r][c4 + 2] = v.z;
      tile[r][c4 + 3] = v.w;
    }
    __syncthreads();
#pragma unroll
    for (int it = 0; it < 2; it++) {
      int i = tid + it * 256;
      int cc = i >> 3, rr = (i & 7) << 3;
      short8 o;
#pragma unroll
      for (int w = 0; w < 8; w++) o[w] = f2bf(tile[rr + w][cc]);
      *(short8*)(d + (size_t)(c0 + cc) * R + r0 + rr) = o;
    }
  }
}

// ---------------- 256x256 8-phase bf16 GEMM (round-2 schedule, proven) -----
// 8 waves (2M x 4N), BK=64, double-buffered 128 KiB LDS, XOR-swizzled chunks:
// LDS slot (row r, 16B-chunk c) holds global k-chunk (c ^ (r&7)); write side
// stays linear (global_load_lds), swizzle applied to global source address.
// Per K-tile: 4 phases, each {stage 1 half-tile of t+1 -> counted vmcnt(6) ->
// s_barrier -> 12x ds_read_b128 -> setprio(1) + 16 MFMA + setprio(0)}.
// Steady state keeps 6-10 loads in flight; never drains vmcnt to 0 mid-loop.
template <int MH, int NH>
__device__ __forceinline__ void phase_mfma(const char* Ab, const char* Bb,
                                           floatx4 (&acc)[8][4], int wm,
                                           int wn, int lane) {
  int l15 = lane & 15, quad = lane >> 4, low3 = lane & 7;
  short8 af[4][2], bv[2][2];
#pragma unroll
  for (int i = 0; i < 4; i++) {
    int row = MH * 128 + wm * 64 + i * 16 + l15;
#pragma unroll
    for (int ks = 0; ks < 2; ks++)
      af[i][ks] =
          *(const short8*)(Ab + row * 128 + (((ks * 4 + quad) ^ low3) << 4));
  }
#pragma unroll
  for (int j = 0; j < 2; j++) {
    int col = NH * 128 + wn * 32 + j * 16 + l15;
#pragma unroll
    for (int ks = 0; ks < 2; ks++)
      bv[j][ks] =
          *(const short8*)(Bb + col * 128 + (((ks * 4 + quad) ^ low3) << 4));
  }
  __builtin_amdgcn_s_setprio(1);
#pragma unroll
  for (int ks = 0; ks < 2; ks++)
#pragma unroll
    for (int i = 0; i < 4; i++)
#pragma unroll
      for (int j = 0; j < 2; j++)
        acc[MH * 4 + i][NH * 2 + j] = __builtin_amdgcn_mfma_f32_16x16x32_bf16(
            af[i][ks], bv[j][ks], acc[MH * 4 + i][NH * 2 + j], 0, 0, 0);
  __builtin_amdgcn_s_setprio(0);
}

template <int KDIM, int NDIM, bool FFN1>
__global__ __launch_bounds__(512, 2) void gemm_kernel(
    const short* __restrict__ A, const short* __restrict__ Bw,
    short* __restrict__ Hout, float* __restrict__ Out,
    const int* __restrict__ counts, const int* __restrict__ offsets,
    const int* __restrict__ tok_of_row, const float* __restrict__ gate_row,
    const int* __restrict__ tileE, const int* __restrict__ tileM,
    const int* __restrict__ ntiles) {
  constexpr int GX = NDIM / 256;
  constexpr int NWG = GX * MAX_TILES;
  static_assert(NWG % 8 == 0, "bijective XCD swizzle needs nwg%8==0");
  constexpr int Q = NWG / 8;
  int flat = blockIdx.y * GX + blockIdx.x;
  int wg = (flat & 7) * Q + (flat >> 3);  // XCD-chunked, bijective
  int ti = wg / GX;
  int nb = wg - ti * GX;
  if (ti >= *ntiles) return;
  int e = tileE[ti], m0 = tileM[ti];
  int Me = counts[e], rowBase = offsets[e];
  int n0 = nb * 256;

  // LDS: [A buf0 32K][A buf1 32K][B buf0 32K][B buf1 32K] = 128 KiB
  __shared__ short lds[65536];

  int tid = threadIdx.x;
  int wid = tid >> 6, lane = tid & 63;
  int wm = wid >> 2, wn = wid & 3;

  // staging geometry: thread covers one 16B chunk; row rt = tid>>3, slot
  // chunk tid&7, swizzled source chunk cs.
  int rt = tid >> 3;
  int cs = (tid & 7) ^ (rt & 7);

  auto aPtr = [&](int mh, int s) {
    int r = m0 + mh * 128 + s * 64 + rt;
    if (r > Me - 1) r = Me - 1;  // clamp pad rows to a valid row
    size_t arow;
    if constexpr (FFN1)
      arow = (size_t)tok_of_row[rowBase + r];  // token-ordered Xbf
    else
      arow = (size_t)(rowBase + r);  // expert-sorted Hbuf
    return A + arow * KDIM + cs * 8;
  };
  auto bPtr = [&](int mh, int s) {
    int r = n0 + mh * 128 + s * 64 + rt;
    return Bw + ((size_t)e * NDIM + r) * (size_t)KDIM + cs * 8;
  };
  const short* pA0a = aPtr(0, 0);
  const short* pA0b = aPtr(0, 1);
  const short* pA1a = aPtr(1, 0);
  const short* pA1b = aPtr(1, 1);
  const short* pB0a = bPtr(0, 0);
  const short* pB0b = bPtr(0, 1);
  const short* pB1a = bPtr(1, 0);
  const short* pB1b = bPtr(1, 1);

  floatx4 acc[8][4];
#pragma unroll
  for (int i = 0; i < 8; i++)
#pragma unroll
    for (int j = 0; j < 4; j++) acc[i][j] = floatx4{0.f, 0.f, 0.f, 0.f};

#define STAGE2(P0, P1, OFF)                               \
  load_lds16(P0, (char*)lds + (OFF) + wid * 1024);        \
  load_lds16(P1, (char*)lds + (OFF) + 8192 + wid * 1024); \
  P0 += 64;                                               \
  P1 += 64;

  // prologue: tile 0 into buf 0, issue order A0,B0,A1,B1 (oldest-first)
  STAGE2(pA0a, pA0b, 0)
  STAGE2(pB0a, pB0b, 65536)
  STAGE2(pA1a, pA1b, 16384)
  STAGE2(pB1a, pB1b, 65536 + 16384)

  constexpr int NT = KDIM / 64;
  int cur = 0;
  for (int t = 0; t < NT; ++t) {
    int nxt = cur ^ 1;
    const char* Ab = (const char*)lds + cur * 32768;
    const char* Bb = (const char*)lds + 65536 + cur * 32768;
    // ---- phase 0: needs A0,B0 of tile t
    if (t + 1 < NT) {
      STAGE2(pA0a, pA0b, nxt * 32768)
      asm volatile("s_waitcnt vmcnt(6)" ::: "memory");
    } else {
      asm volatile("s_waitcnt vmcnt(4)" ::: "memory");
    }
    __builtin_amdgcn_s_barrier();
    phase_mfma<0, 0>(Ab, Bb, acc, wm, wn, lane);
    // ---- phase 1: needs A1
    if (t + 1 < NT) {
      STAGE2(pB0a, pB0b, 65536 + nxt * 32768)
      asm volatile("s_waitcnt vmcnt(6)" ::: "memory");
    } else {
      asm volatile("s_waitcnt vmcnt(2)" ::: "memory");
    }
    __builtin_amdgcn_s_barrier();
    phase_mfma<1, 0>(Ab, Bb, acc, wm, wn, lane);
    // ---- phase 2: needs B1
    if (t + 1 < NT) {
      STAGE2(pA1a, pA1b, 16384 + nxt * 32768)
      asm volatile("s_waitcnt vmcnt(6)" ::: "memory");
    } else {
      asm volatile("s_waitcnt vmcnt(0)" ::: "memory");
    }
    __builtin_amdgcn_s_barrier();
    phase_mfma<0, 1>(Ab, Bb, acc, wm, wn, lane);
    // ---- phase 3: everything already drained
    if (t + 1 < NT) {
      STAGE2(pB1a, pB1b, 65536 + 16384 + nxt * 32768)
    }
    phase_mfma<1, 1>(Ab, Bb, acc, wm, wn, lane);
    // tile-end barrier: all waves done reading buf[cur] before anyone
    // stages tile t+2 into it at next p0. sched_barrier pins MFMAs above.
    __builtin_amdgcn_sched_barrier(0);
    __builtin_amdgcn_s_barrier();
    cur = nxt;
  }
#undef STAGE2

  // epilogue. C/D layout: col = lane&15, row = (lane>>4)*4 + reg  [m89]
  int l15 = lane & 15;
#pragma unroll
  for (int i = 0; i < 8; i++) {
    int mb = (i >> 2) * 128 + wm * 64 + (i & 3) * 16 + ((lane >> 4) << 2);
#pragma unroll
    for (int r = 0; r < 4; r++) {
      int m = m0 + mb + r;
      if (m < Me) {
        int grow = rowBase + m;
        if constexpr (FFN1) {
#pragma unroll
          for (int j = 0; j < 4; j++) {
            float v = acc[i][j][r];
            v = v > 0.f ? v : 0.f;
            Hout[(size_t)grow * NDIM + n0 + (j >> 1) * 128 + wn * 32 +
                 (j & 1) * 16 + l15] = f2bf(v);
          }
        } else {
          int tk = tok_of_row[grow];
          float g = gate_row[grow];
#pragma unroll
          for (int j = 0; j < 4; j++)
            Out[(size_t)tk * NDIM + n0 + (j >> 1) * 128 + wn * 32 +
                (j & 1) * 16 + l15] = acc[i][j][r] * g;
        }
      }
    }
  }
}

extern "C" void kernel_launch(void* const* d_in, const int* in_sizes, int n_in,
                              void* d_out, int out_size, void* d_ws,
                              size_t ws_size, hipStream_t stream) {
  const float* x = (const float*)d_in[0];
  const float* w1 = (const float*)d_in[1];
  const float* w2 = (const float*)d_in[2];
  const float* rw = (const float*)d_in[3];
  const float* rb = (const float*)d_in[4];
  float* out = (float*)d_out;
  float* loss_out = out + (out_size - 1);  // loss scalar at tail

  char* ws = (char*)d_ws;
  size_t o = 0;
  auto alloc = [&](size_t bytes) {
    char* p = ws + o;
    o += (bytes + 255) & ~(size_t)255;
    return p;
  };
  short* W1T = (short*)alloc((size_t)NEXP * FDIM * DDIM * 2);  // [E][F][D] bf16
  short* W2T = (short*)alloc((size_t)NEXP * DDIM * FDIM * 2);  // [E][D][F] bf16
  short* Xbf = (short*)alloc((size_t)T_TOK * DDIM * 2);        // token-order x
  short* Hbuf = (short*)alloc((size_t)T_TOK * FDIM * 2);       // relu(h) bf16
  int* tok_of_row = (int*)alloc(T_TOK * 4);
  float* gate_row = (float*)alloc(T_TOK * 4);
  int* expert_t = (int*)alloc(T_TOK * 4);
  float* gate_t = (float*)alloc(T_TOK * 4);
  int* counts = (int*)alloc(64);
  int* offsets = (int*)alloc(64);
  int* tileE = (int*)alloc(MAX_TILES * 4);
  int* tileM = (int*)alloc(MAX_TILES * 4);
  int* ntiles = (int*)alloc(64);

  // router: logits + gate + x->bf16 (small, fast)
  router_kernel<<<T_TOK / 4, 256, 0, stream>>>(x, rw, rb, expert_t, gate_t,
                                               Xbf);
  // transpose both weights; block 0 runs the finalize scan concurrently
  transfin_kernel<<<1 + 8192 + 8192, 256, 0, stream>>>(
      w1, w2, W1T, W2T, expert_t, gate_t, counts, offsets, loss_out, tileE,
      tileM, ntiles, tok_of_row, gate_row);

  // FFN1: [n_e,1024] @ [1024,4096] -> relu -> Hbuf bf16 (A via tok_of_row)
  gemm_kernel<DDIM, FDIM, true>
      <<<dim3(FDIM / 256, MAX_TILES), 512, 0, stream>>>(
          Xbf, W1T, Hbuf, nullptr, counts, offsets, tok_of_row, nullptr,
          tileE, tileM, ntiles);
  // FFN2: [n_e,4096] @ [4096,1024] -> *gate -> scatter to out fp32
  gemm_kernel<FDIM, DDIM, false>
      <<<dim3(DDIM / 256, MAX_TILES), 512, 0, stream>>>(
          Hbuf, W2T, nullptr, out, counts, offsets, tok_of_row, gate_row,
          tileE, tileM, ntiles);
}